// Round 10
// baseline (453.932 us; speedup 1.0000x reference)
//
#include <hip/hip_runtime.h>
#include <math.h>

#define NB 64
#define NS 2048
#define ND 512
#define MTOT (NB * NS)  // 131072
#define CCLIP 10.0f

typedef _Float16 f16x8 __attribute__((ext_vector_type(8)));
typedef _Float16 f16x4 __attribute__((ext_vector_type(4)));
typedef float f32x4 __attribute__((ext_vector_type(4)));

__device__ __forceinline__ float tanh_fast(float x) {
  float e = __expf(2.f * x);
  return 1.f - 2.f * __builtin_amdgcn_rcpf(e + 1.f);
}

// ---------------------------------------------------------------------------
// cvtw2: Wref fp32 -> fp16 in FRAGMENT-MAJOR order so a wave's bf[j] load is
// one coalesced global_load_dwordx4 (16 B/lane), no LDS staging for B:
//   Wc[((kt*32 + c32)*64 + lane)*8 + e] = Wref[c32*16 + (lane&15)]
//                                             [kt*32 + (lane>>4)*8 + e]
// (c32 = col/16; lane = quad*16+l15; identical element semantics to the old
//  sB[kg][d][8] staging, verified: col = c32*16+l15, k = kt*32+quad*8+e.)
// ---------------------------------------------------------------------------
__global__ __launch_bounds__(256) void cvtw2_kernel(
    const float* __restrict__ Wref, _Float16* __restrict__ Wc) {
  const int g = blockIdx.x * 256 + threadIdx.x;  // < 32768
  const int lane = g & 63;
  const int rest = g >> 6;        // 0..511 = kt*32 + c32
  const int c32 = rest & 31;
  const int kt = rest >> 5;
  const int col = c32 * 16 + (lane & 15);
  const int k = kt * 32 + ((lane >> 4) & 3) * 8;
  const float4* in = (const float4*)(Wref + (size_t)col * ND + k);
  float4 a = in[0];
  float4 b = in[1];
  f16x8 o;
  o[0] = (_Float16)a.x; o[1] = (_Float16)a.y;
  o[2] = (_Float16)a.z; o[3] = (_Float16)a.w;
  o[4] = (_Float16)b.x; o[5] = (_Float16)b.y;
  o[6] = (_Float16)b.z; o[7] = (_Float16)b.w;
  *(f16x8*)(Wc + (size_t)g * 8) = o;
}

// ---------------------------------------------------------------------------
// qk: q[b,d] = sum_k W_q[d,k] * tgt[b,k]
// ---------------------------------------------------------------------------
__global__ __launch_bounds__(256) void qk_kernel(const float* __restrict__ tgt,
                                                 const float* __restrict__ Wq,
                                                 float* __restrict__ q_ws) {
  const int b = blockIdx.x >> 1;
  const int d = ((blockIdx.x & 1) << 8) + threadIdx.x;
  __shared__ float tl[ND];
  tl[threadIdx.x] = tgt[b * ND + threadIdx.x];
  tl[threadIdx.x + 256] = tgt[b * ND + threadIdx.x + 256];
  __syncthreads();
  const float4* wr = (const float4*)(Wq + (size_t)d * ND);
  float acc = 0.f;
#pragma unroll 8
  for (int k4 = 0; k4 < ND / 4; ++k4) {
    float4 w4 = wr[k4];
    acc += w4.x * tl[4 * k4 + 0] + w4.y * tl[4 * k4 + 1] +
           w4.z * tl[4 * k4 + 2] + w4.w * tl[4 * k4 + 3];
  }
  q_ws[b * ND + d] = acc;
}

// ---------------------------------------------------------------------------
// gemm: block = 64 src rows x FULL N=512, K=512 in 16 kt of 32.
// 256 threads / 4 waves; wave cq owns cols cq*128..+127 -> acc[4][8] f32x4.
// NEW STRUCTURE (round-5 post-mortem: barrier-locked B staging serialized
// MFMA+LDS+VALU+staging into 6400cyc/kt with MfmaUtil 16%):
//  - B: direct coalesced register loads from fragment-major Wc (L2-resident
//    512 KB, shared chip-wide). No sB, no gl2lds, no triple-buffer, no asm
//    waitcnt. B traffic 64 KB/CU/kt from L2 -- own pipe, overlaps MFMA.
//  - A: tiny 2x4KB LDS double-buffer (proven round-1 staging map), one plain
//    __syncthreads per kt. With no gl2lds in flight the barrier's vmcnt
//    drain only covers already-consumed loads (~free).
//  - 2 blocks/CU (LDS ~9.3 KB, ~230 regs): independent async blocks hide
//    each other's barrier/latency bubbles (m114 co-scheduling).
// Epilogue + fused d' partial reused verbatim from round-1 (passed).
// ---------------------------------------------------------------------------
__global__ __launch_bounds__(256, 2) void gemm_kernel(
    const float* __restrict__ src, const _Float16* __restrict__ Wc,
    const float* __restrict__ q_ws, const float* __restrict__ v,
    float* __restrict__ out_logit, float* __restrict__ out_probs_w,
    float* __restrict__ dp_ws) {
  __shared__ __align__(16) _Float16 sAall[2 * 4 * 64 * 8];  // 2 x 4 KB
  __shared__ float ured[4 * 64];                            // 1 KB
  __shared__ float wsh[64];                                 // 256 B

  const int tid = threadIdx.x;
  const int lane = tid & 63;
  const int w = tid >> 6;      // wave 0..3 = col-quarter cq
  const int cq = w;
  const int s0 = blockIdx.x << 6;
  const int bb = blockIdx.x >> 5;

  const int quad = lane >> 4;
  const int l15 = lane & 15;

  // A staging: 4 consecutive lanes cover one row's 32-B k-window per kt
  const int ar = tid >> 2;   // row 0..63
  const int akg = tid & 3;   // k-group
  const float4* ap =
      (const float4*)(src + ((size_t)(s0 + ar) << 9)) + akg * 2;
  const int aoff = akg * 512 + ((ar ^ (akg << 2)) << 3);  // swizzled f16 idx

  // B fragment base for this wave: j stride = 64 lanes * 8 f16 = 512
  const _Float16* wb = Wc + ((size_t)(cq * 8) * 64 + lane) * 8;

  f32x4 acc[4][8];
#pragma unroll
  for (int i = 0; i < 4; ++i)
#pragma unroll
    for (int j = 0; j < 8; ++j) acc[i][j] = (f32x4){0.f, 0.f, 0.f, 0.f};

  // prologue: stage A(0) into buf 0
  {
    float4 x0 = ap[0];
    float4 x1 = ap[1];
    f16x8 hh;
    hh[0] = (_Float16)x0.x; hh[1] = (_Float16)x0.y;
    hh[2] = (_Float16)x0.z; hh[3] = (_Float16)x0.w;
    hh[4] = (_Float16)x1.x; hh[5] = (_Float16)x1.y;
    hh[6] = (_Float16)x1.z; hh[7] = (_Float16)x1.w;
    *(f16x8*)(sAall + aoff) = hh;
  }
  __syncthreads();

  for (int kt = 0; kt < 16; ++kt) {
    const _Float16* sA = sAall + (kt & 1) * 2048;

    // B: 8 coalesced register loads from L2-resident Wc
    f16x8 bf[8];
    const _Float16* wk = wb + (size_t)(kt * 32) * 512;
#pragma unroll
    for (int j = 0; j < 8; ++j)
      bf[j] = *(const f16x8*)(wk + (size_t)j * 512);

    // A fragments from LDS
    f16x8 af[4];
#pragma unroll
    for (int i = 0; i < 4; ++i) {
      const int row = 16 * i + l15;
      af[i] = *(const f16x8*)(sA + quad * 512 + ((row ^ (quad << 2)) << 3));
    }

    // stage A(kt+1) into the other buffer
    if (kt < 15) {
      float4 x0 = ap[(kt + 1) * 8];
      float4 x1 = ap[(kt + 1) * 8 + 1];
      f16x8 hh;
      hh[0] = (_Float16)x0.x; hh[1] = (_Float16)x0.y;
      hh[2] = (_Float16)x0.z; hh[3] = (_Float16)x0.w;
      hh[4] = (_Float16)x1.x; hh[5] = (_Float16)x1.y;
      hh[6] = (_Float16)x1.z; hh[7] = (_Float16)x1.w;
      *(f16x8*)(sAall + ((kt + 1) & 1) * 2048 + aoff) = hh;
    }

#pragma unroll
    for (int i = 0; i < 4; ++i)
#pragma unroll
      for (int j = 0; j < 8; ++j)
        acc[i][j] = __builtin_amdgcn_mfma_f32_16x16x32_f16(af[i], bf[j],
                                                           acc[i][j], 0, 0, 0);

    __syncthreads();
  }

  // epilogue: pu[row] = sum over this wave's 128 cols of tanh(.+q)*v
  float pu[4][4];
#pragma unroll
  for (int i = 0; i < 4; ++i)
#pragma unroll
    for (int r = 0; r < 4; ++r) pu[i][r] = 0.f;

#pragma unroll
  for (int j = 0; j < 8; ++j) {
    const int dl = cq * 128 + 16 * j + l15;
    const float qq = q_ws[bb * ND + dl];
    const float vv = v[dl];
#pragma unroll
    for (int i = 0; i < 4; ++i) {
      f32x4 a = acc[i][j];
#pragma unroll
      for (int r = 0; r < 4; ++r) pu[i][r] += tanh_fast(a[r] + qq) * vv;
    }
  }

#pragma unroll
  for (int i = 0; i < 4; ++i)
#pragma unroll
    for (int r = 0; r < 4; ++r) {
      float x = pu[i][r];
      x += __shfl_xor(x, 1, 16);
      x += __shfl_xor(x, 2, 16);
      x += __shfl_xor(x, 4, 16);
      x += __shfl_xor(x, 8, 16);
      pu[i][r] = x;
    }

  if (l15 == 0) {
#pragma unroll
    for (int i = 0; i < 4; ++i)
#pragma unroll
      for (int r = 0; r < 4; ++r)
        ured[w * 64 + 16 * i + quad * 4 + r] = pu[i][r];
  }
  __syncthreads();
  if (tid < 64) {
    const float u =
        ured[tid] + ured[64 + tid] + ured[128 + tid] + ured[192 + tid];
    const float lg = CCLIP * tanhf(u);
    out_logit[s0 + tid] = lg;
    const float wexp = expf(lg - CCLIP);
    out_probs_w[s0 + tid] = wexp;
    wsh[tid] = wexp;
  }
  __syncthreads();

  // fused d' partial: dp_part[d] = sum_{r=0..63} w_r * src[s0+r][d]
  const int c4 = tid & 127;   // float4 column index (0..127)
  const int half = tid >> 7;  // row half 0/1
  const float4* sp = (const float4*)(src + ((size_t)s0 << 9)) + c4;
  float dx = 0.f, dy = 0.f, dz = 0.f, dw = 0.f;
  const int r0 = half << 5;
#pragma unroll 4
  for (int r = r0; r < r0 + 32; ++r) {
    const float wr = wsh[r];
    const float4 x = sp[(size_t)r * 128];
    dx += wr * x.x; dy += wr * x.y; dz += wr * x.z; dw += wr * x.w;
  }
  // combine the two row-halves via LDS (reuse sAall as scratch, 2 KB needed)
  float4* red4 = (float4*)sAall;
  if (half) {
    float4 o; o.x = dx; o.y = dy; o.z = dz; o.w = dw;
    red4[c4] = o;
  }
  __syncthreads();
  if (!half) {
    float4 o = red4[c4];
    o.x += dx; o.y += dy; o.z += dz; o.w += dw;
    *(float4*)(dp_ws + (size_t)blockIdx.x * ND + (c4 << 2)) = o;
  }
}

// ---------------------------------------------------------------------------
// fin: per b: S = sum w (parked in out_probs); probs *= 1/S;
//      d'[d] = (sum of 32 per-block partials)/S
// ---------------------------------------------------------------------------
__global__ __launch_bounds__(256) void fin_kernel(
    const float* __restrict__ dp_ws, float* __restrict__ out_dp,
    float* __restrict__ out_probs) {
  const int b = blockIdx.x;
  const int tid = threadIdx.x;
  __shared__ float red[4];
  __shared__ float s_inv;

  float x = 0.f;
  for (int idx = tid; idx < NS; idx += 256) x += out_probs[b * NS + idx];
#pragma unroll
  for (int m = 32; m; m >>= 1) x += __shfl_xor(x, m, 64);
  if ((tid & 63) == 0) red[tid >> 6] = x;
  __syncthreads();
  if (tid == 0) s_inv = 1.f / (red[0] + red[1] + red[2] + red[3]);
  __syncthreads();
  const float inv = s_inv;

  for (int idx = tid; idx < NS; idx += 256)
    out_probs[b * NS + idx] *= inv;

  for (int d = tid; d < ND; d += 256) {
    float acc = 0.f;
#pragma unroll 8
    for (int ch = 0; ch < 32; ++ch)
      acc += dp_ws[(size_t)(b * 32 + ch) * ND + d];
    out_dp[b * ND + d] = acc * inv;
  }
}

// ---------------------------------------------------------------------------
extern "C" void kernel_launch(void* const* d_in, const int* in_sizes, int n_in,
                              void* d_out, int out_size, void* d_ws,
                              size_t ws_size, hipStream_t stream) {
  const float* src = (const float*)d_in[0];   // [64,2048,512]
  const float* tgt = (const float*)d_in[1];   // [64,1,512]
  const float* Wq = (const float*)d_in[2];    // [512,512]
  const float* Wref = (const float*)d_in[3];  // [512,512]
  const float* v = (const float*)d_in[4];     // [512]

  float* out = (float*)d_out;
  float* out_dp = out;                        // 64*512
  float* out_probs = out + NB * ND;           // 64*2048 (holds w pre-fin)
  float* out_logit = out + NB * ND + NB * NS; // 64*2048

  // workspace: 524288 + 131072 + 4194304 = 4,849,664 B (proven footprint)
  char* ws = (char*)d_ws;
  _Float16* Wc = (_Float16*)ws;               // 512*512*2 =   524,288 B
  float* q_ws = (float*)(ws + 524288);        // 64*512*4  =   131,072 B
  float* dp_ws = (float*)(ws + 655360);       // 2048*512*4 = 4,194,304 B

  cvtw2_kernel<<<128, 256, 0, stream>>>(Wref, Wc);
  qk_kernel<<<2 * NB, 256, 0, stream>>>(tgt, Wq, q_ws);
  gemm_kernel<<<MTOT / 64, 256, 0, stream>>>(src, Wc, q_ws, v, out_logit,
                                             out_probs, dp_ws);
  fin_kernel<<<NB, 256, 0, stream>>>(dp_ws, out_dp, out_probs);
}